// Round 1
// baseline (206.239 us; speedup 1.0000x reference)
//
#include <hip/hip_runtime.h>
#include <math.h>

#define NB   8
#define NH   32
#define LQ   4
#define LK   4096
#define DD   128
#define SCALE_F 0.08838834764831845f

// 256 blocks (one per (b,h)), 1024 threads = 16 waves.
// Each wave handles a contiguous 256-key slice; each 32-lane half-wave is an
// independent online-softmax stream over interleaved keys (2 per iteration,
// float4 loads = 16B/lane coalescing sweet spot).
__global__ __launch_bounds__(1024, 4)
void attn_decode_kernel(const float* __restrict__ Q, const float* __restrict__ K,
                        const float* __restrict__ V, const float* __restrict__ Msk,
                        float* __restrict__ Out)
{
    __shared__ float o_buf[16][LQ][DD];   // 32 KB: per-wave partial outputs
    __shared__ float ml_buf[16][LQ][2];   // per-wave running (m, l)

    const int bh   = blockIdx.x;          // 0..255
    const int b    = bh >> 5;             // H = 32
    const int tid  = threadIdx.x;
    const int wave = tid >> 6;            // 0..15
    const int lane = tid & 63;
    const int half = lane >> 5;           // 0/1 : which key of the pair
    const int sub  = lane & 31;           // 0..31 : which float4 of the row

    const float* qp = Q   + (size_t)bh * (LQ * DD);
    const float* kp = K   + (size_t)bh * (LK * DD);
    const float* vp = V   + (size_t)bh * (LK * DD);
    const float* mp = Msk + (size_t)b  * (LQ * LK);

    // Q fragments: lane holds q[qi][sub*4 .. sub*4+3]
    float4 q4[LQ];
#pragma unroll
    for (int qi = 0; qi < LQ; ++qi)
        q4[qi] = *(const float4*)(qp + qi * DD + sub * 4);

    float m_run[LQ], l_run[LQ];
    float4 o4[LQ];
#pragma unroll
    for (int qi = 0; qi < LQ; ++qi) {
        m_run[qi] = -INFINITY;
        l_run[qi] = 0.0f;
        o4[qi].x = 0.0f; o4[qi].y = 0.0f; o4[qi].z = 0.0f; o4[qi].w = 0.0f;
    }

    const int j0 = wave * 256;            // this wave's contiguous key slice
    for (int t = 0; t < 256; t += 4) {
        const int ja = j0 + t + half;     // half 0 -> j, half 1 -> j+1
        const int jb = ja + 2;

        // issue all 4 vector loads up front (2 KB / wave / iteration per array)
        const float4 ka = *(const float4*)(kp + (size_t)ja * DD + sub * 4);
        const float4 kb = *(const float4*)(kp + (size_t)jb * DD + sub * 4);
        const float4 va = *(const float4*)(vp + (size_t)ja * DD + sub * 4);
        const float4 vb = *(const float4*)(vp + (size_t)jb * DD + sub * 4);

        // per-lane partial dot products
        float sa[LQ], sb[LQ];
#pragma unroll
        for (int qi = 0; qi < LQ; ++qi) {
            sa[qi] = ka.x*q4[qi].x + ka.y*q4[qi].y + ka.z*q4[qi].z + ka.w*q4[qi].w;
            sb[qi] = kb.x*q4[qi].x + kb.y*q4[qi].y + kb.z*q4[qi].z + kb.w*q4[qi].w;
        }
        // reduce across the 32-lane half (xor masks < 32 stay inside the half)
#pragma unroll
        for (int msk = 1; msk <= 16; msk <<= 1) {
#pragma unroll
            for (int qi = 0; qi < LQ; ++qi) {
                sa[qi] += __shfl_xor(sa[qi], msk, 64);
                sb[qi] += __shfl_xor(sb[qi], msk, 64);
            }
        }

        // online softmax update: one rescale per 2 keys
#pragma unroll
        for (int qi = 0; qi < LQ; ++qi) {
            const float s_a = sa[qi] * SCALE_F + mp[qi * LK + ja];
            const float s_b = sb[qi] * SCALE_F + mp[qi * LK + jb];
            const float mn  = fmaxf(m_run[qi], fmaxf(s_a, s_b));   // v_max3
            const float f   = __expf(m_run[qi] - mn);
            const float pa  = __expf(s_a - mn);
            const float pb  = __expf(s_b - mn);
            m_run[qi] = mn;
            l_run[qi] = l_run[qi] * f + pa + pb;
            o4[qi].x = o4[qi].x * f + pa * va.x + pb * vb.x;
            o4[qi].y = o4[qi].y * f + pa * va.y + pb * vb.y;
            o4[qi].z = o4[qi].z * f + pa * va.z + pb * vb.z;
            o4[qi].w = o4[qi].w * f + pa * va.w + pb * vb.w;
        }
    }

    // combine the two half-wave streams in-register (same dims, lanes l and l^32)
#pragma unroll
    for (int qi = 0; qi < LQ; ++qi) {
        const float m_o = __shfl_xor(m_run[qi], 32, 64);
        const float l_o = __shfl_xor(l_run[qi], 32, 64);
        float4 oo;
        oo.x = __shfl_xor(o4[qi].x, 32, 64);
        oo.y = __shfl_xor(o4[qi].y, 32, 64);
        oo.z = __shfl_xor(o4[qi].z, 32, 64);
        oo.w = __shfl_xor(o4[qi].w, 32, 64);
        const float M  = fmaxf(m_run[qi], m_o);
        const float fo = __expf(m_run[qi] - M);
        const float fx = __expf(m_o - M);
        o4[qi].x = o4[qi].x * fo + oo.x * fx;
        o4[qi].y = o4[qi].y * fo + oo.y * fx;
        o4[qi].z = o4[qi].z * fo + oo.z * fx;
        o4[qi].w = o4[qi].w * fo + oo.w * fx;
        l_run[qi] = l_run[qi] * fo + l_o * fx;
        m_run[qi] = M;
    }

    // stage per-wave partials to LDS
    if (half == 0) {
#pragma unroll
        for (int qi = 0; qi < LQ; ++qi)
            *(float4*)&o_buf[wave][qi][sub * 4] = o4[qi];
        if (sub == 0) {
#pragma unroll
            for (int qi = 0; qi < LQ; ++qi) {
                ml_buf[wave][qi][0] = m_run[qi];
                ml_buf[wave][qi][1] = l_run[qi];
            }
        }
    }
    __syncthreads();

    // final cross-wave combine: 512 threads, one (qi, d) each
    if (tid < LQ * DD) {
        const int qi = tid >> 7;
        const int d  = tid & 127;
        float M = -INFINITY;
#pragma unroll
        for (int w = 0; w < 16; ++w)
            M = fmaxf(M, ml_buf[w][qi][0]);
        float Lsum = 0.0f, Osum = 0.0f;
#pragma unroll
        for (int w = 0; w < 16; ++w) {
            const float f = __expf(ml_buf[w][qi][0] - M);
            Lsum += ml_buf[w][qi][1] * f;
            Osum += o_buf[w][qi][d] * f;
        }
        Out[(size_t)bh * (LQ * DD) + tid] = Osum / Lsum;
    }
}

extern "C" void kernel_launch(void* const* d_in, const int* in_sizes, int n_in,
                              void* d_out, int out_size, void* d_ws, size_t ws_size,
                              hipStream_t stream)
{
    const float* q   = (const float*)d_in[0];
    const float* k   = (const float*)d_in[1];
    const float* v   = (const float*)d_in[2];
    const float* msk = (const float*)d_in[3];
    float* out = (float*)d_out;

    attn_decode_kernel<<<dim3(NB * NH), dim3(1024), 0, stream>>>(q, k, v, msk, out);
}

// Round 2
// 206.221 us; speedup vs baseline: 1.0001x; 1.0001x over previous
//
#include <hip/hip_runtime.h>
#include <math.h>

#define NB   8
#define NH   32
#define LQ   4
#define LK   4096
#define DD   128
#define SCALE_F 0.08838834764831845f

// 256 blocks (one per (b,h)), 1024 threads = 16 waves.
// Each wave owns a contiguous 256-key slice. Within a wave: 4 groups of 16
// lanes; each group processes one key per iteration (4 keys/wave/iter), each
// lane covering an 8-float slice of D (two float4 loads, 32 B/lane).
// QK reduce is a 4-step shfl_xor within the 16-lane group. K/V loads are
// software-pipelined one iteration ahead.
__global__ __launch_bounds__(1024, 4)
void attn_decode_kernel(const float* __restrict__ Q, const float* __restrict__ K,
                        const float* __restrict__ V, const float* __restrict__ Msk,
                        float* __restrict__ Out)
{
    __shared__ float o_buf[16][LQ][DD];   // 32 KB: per-wave partial outputs
    __shared__ float ml_buf[16][LQ][2];   // per-wave running (m, l)

    const int bh   = blockIdx.x;          // 0..255
    const int b    = bh >> 5;             // H = 32
    const int tid  = threadIdx.x;
    const int wave = tid >> 6;            // 0..15
    const int lane = tid & 63;
    const int grp  = lane >> 4;           // 0..3 : which key of the 4-key iter
    const int sl   = lane & 15;           // d-slice: d0 = sl*8

    const float* qp = Q   + (size_t)bh * (LQ * DD);
    const float* kp = K   + (size_t)bh * (LK * DD);
    const float* vp = V   + (size_t)bh * (LK * DD);
    const float* mp = Msk + (size_t)b  * (LQ * LK);

    // Q fragments: lane holds q[qi][sl*8 .. sl*8+7]
    float4 qa[LQ], qb[LQ];
#pragma unroll
    for (int qi = 0; qi < LQ; ++qi) {
        qa[qi] = *(const float4*)(qp + qi * DD + sl * 8);
        qb[qi] = *(const float4*)(qp + qi * DD + sl * 8 + 4);
    }

    float m_run[LQ], l_run[LQ];
    float4 oa[LQ], ob[LQ];
#pragma unroll
    for (int qi = 0; qi < LQ; ++qi) {
        m_run[qi] = -INFINITY;
        l_run[qi] = 0.0f;
        oa[qi].x = oa[qi].y = oa[qi].z = oa[qi].w = 0.0f;
        ob[qi].x = ob[qi].y = ob[qi].z = ob[qi].w = 0.0f;
    }

    const int j0 = wave * 256 + grp;      // this group's first key

    // software pipeline: preload K/V for t=0
    const float* kr = kp + (size_t)j0 * DD + sl * 8;
    const float* vr = vp + (size_t)j0 * DD + sl * 8;
    float4 ka = *(const float4*)(kr);
    float4 kb = *(const float4*)(kr + 4);
    float4 va = *(const float4*)(vr);
    float4 vb = *(const float4*)(vr + 4);

    for (int t = 0; t < 256; t += 4) {
        const int j = j0 + t;             // current key for this group
        // next iteration's row (clamped on the last iteration: reload = L1 hit)
        const int jn = j + ((t < 252) ? 4 : 0);

        // per-lane partial dot for this group's key (consumes ka/kb)
        float s[LQ];
#pragma unroll
        for (int qi = 0; qi < LQ; ++qi) {
            s[qi] = ka.x*qa[qi].x + ka.y*qa[qi].y + ka.z*qa[qi].z + ka.w*qa[qi].w
                  + kb.x*qb[qi].x + kb.y*qb[qi].y + kb.z*qb[qi].z + kb.w*qb[qi].w;
        }

        // prefetch next K (ka/kb dead after the dot)
        const float* krn = kp + (size_t)jn * DD + sl * 8;
        ka = *(const float4*)(krn);
        kb = *(const float4*)(krn + 4);

        // reduce across the 16-lane group (xor masks < 16 stay inside)
#pragma unroll
        for (int msk = 1; msk <= 8; msk <<= 1) {
#pragma unroll
            for (int qi = 0; qi < LQ; ++qi)
                s[qi] += __shfl_xor(s[qi], msk, 64);
        }

        // online softmax update (consumes va/vb)
#pragma unroll
        for (int qi = 0; qi < LQ; ++qi) {
            const float sv = s[qi] * SCALE_F + mp[qi * LK + j];
            const float mn = fmaxf(m_run[qi], sv);
            const float f  = __expf(m_run[qi] - mn);
            const float p  = __expf(sv - mn);
            m_run[qi] = mn;
            l_run[qi] = l_run[qi] * f + p;
            oa[qi].x = oa[qi].x * f + p * va.x;
            oa[qi].y = oa[qi].y * f + p * va.y;
            oa[qi].z = oa[qi].z * f + p * va.z;
            oa[qi].w = oa[qi].w * f + p * va.w;
            ob[qi].x = ob[qi].x * f + p * vb.x;
            ob[qi].y = ob[qi].y * f + p * vb.y;
            ob[qi].z = ob[qi].z * f + p * vb.z;
            ob[qi].w = ob[qi].w * f + p * vb.w;
        }

        // prefetch next V (va/vb dead after the o-update)
        const float* vrn = vp + (size_t)jn * DD + sl * 8;
        va = *(const float4*)(vrn);
        vb = *(const float4*)(vrn + 4);
    }

    // combine the 4 group-streams: lanes sl, sl^16, sl^32, sl^48 share a d-slice
#pragma unroll
    for (int xm = 16; xm <= 32; xm <<= 1) {
#pragma unroll
        for (int qi = 0; qi < LQ; ++qi) {
            const float m_o = __shfl_xor(m_run[qi], xm, 64);
            const float l_o = __shfl_xor(l_run[qi], xm, 64);
            float4 xa, xb;
            xa.x = __shfl_xor(oa[qi].x, xm, 64);
            xa.y = __shfl_xor(oa[qi].y, xm, 64);
            xa.z = __shfl_xor(oa[qi].z, xm, 64);
            xa.w = __shfl_xor(oa[qi].w, xm, 64);
            xb.x = __shfl_xor(ob[qi].x, xm, 64);
            xb.y = __shfl_xor(ob[qi].y, xm, 64);
            xb.z = __shfl_xor(ob[qi].z, xm, 64);
            xb.w = __shfl_xor(ob[qi].w, xm, 64);
            const float M  = fmaxf(m_run[qi], m_o);
            const float fo = __expf(m_run[qi] - M);
            const float fx = __expf(m_o - M);
            oa[qi].x = oa[qi].x * fo + xa.x * fx;
            oa[qi].y = oa[qi].y * fo + xa.y * fx;
            oa[qi].z = oa[qi].z * fo + xa.z * fx;
            oa[qi].w = oa[qi].w * fo + xa.w * fx;
            ob[qi].x = ob[qi].x * fo + xb.x * fx;
            ob[qi].y = ob[qi].y * fo + xb.y * fx;
            ob[qi].z = ob[qi].z * fo + xb.z * fx;
            ob[qi].w = ob[qi].w * fo + xb.w * fx;
            l_run[qi] = l_run[qi] * fo + l_o * fx;
            m_run[qi] = M;
        }
    }

    // stage per-wave partials to LDS (lanes 0..15 hold the combined result)
    if (grp == 0) {
#pragma unroll
        for (int qi = 0; qi < LQ; ++qi) {
            *(float4*)&o_buf[wave][qi][sl * 8]     = oa[qi];
            *(float4*)&o_buf[wave][qi][sl * 8 + 4] = ob[qi];
        }
        if (sl == 0) {
#pragma unroll
            for (int qi = 0; qi < LQ; ++qi) {
                ml_buf[wave][qi][0] = m_run[qi];
                ml_buf[wave][qi][1] = l_run[qi];
            }
        }
    }
    __syncthreads();

    // final cross-wave combine: 512 threads, one (qi, d) each
    if (tid < LQ * DD) {
        const int qi = tid >> 7;
        const int d  = tid & 127;
        float M = -INFINITY;
#pragma unroll
        for (int w = 0; w < 16; ++w)
            M = fmaxf(M, ml_buf[w][qi][0]);
        float Lsum = 0.0f, Osum = 0.0f;
#pragma unroll
        for (int w = 0; w < 16; ++w) {
            const float f = __expf(ml_buf[w][qi][0] - M);
            Lsum += ml_buf[w][qi][1] * f;
            Osum += o_buf[w][qi][d] * f;
        }
        Out[(size_t)bh * (LQ * DD) + tid] = Osum / Lsum;
    }
}

extern "C" void kernel_launch(void* const* d_in, const int* in_sizes, int n_in,
                              void* d_out, int out_size, void* d_ws, size_t ws_size,
                              hipStream_t stream)
{
    const float* q   = (const float*)d_in[0];
    const float* k   = (const float*)d_in[1];
    const float* v   = (const float*)d_in[2];
    const float* msk = (const float*)d_in[3];
    float* out = (float*)d_out;

    attn_decode_kernel<<<dim3(NB * NH), dim3(1024), 0, stream>>>(q, k, v, msk, out);
}